// Round 11
// baseline (3611.098 us; speedup 1.0000x reference)
//
#include <hip/hip_runtime.h>
#include <math.h>

#define NN 40000
#define NE 640000
#define HH 128
#define OUTD 10

__device__ __forceinline__ float reluf(float x){ return x > 0.f ? x : 0.f; }

// ---------------- CSR build ----------------
__global__ void init_ws_kernel(int* cnt, int* flags) {
    int i = blockIdx.x*blockDim.x + threadIdx.x;
    if (i < NN) cnt[i] = 0;
    if (i < 4)  flags[i] = 0;
}

__global__ void count_kernel(const int* __restrict__ ei, int* __restrict__ cnt) {
    int e = blockIdx.x*blockDim.x + threadIdx.x;
    if (e < NE) atomicAdd(&cnt[ei[NE + e]], 1);
}

// dinv = 1.0f / sqrtf(deg)  -- two correctly-rounded fp32 ops, matching np 1/np.sqrt
__global__ void dinv_kernel(const int* __restrict__ cnt, float* __restrict__ dinv) {
    int i = blockIdx.x*blockDim.x + threadIdx.x;
    if (i < NN) dinv[i] = __fdiv_rn(1.0f, __fsqrt_rn((float)(cnt[i] + 1)));
}

__global__ __launch_bounds__(256) void scan_a_kernel(const int* __restrict__ cnt,
                                                     int* __restrict__ rowptr,
                                                     int* __restrict__ bsum) {
    __shared__ int sh[256];
    int t = threadIdx.x;
    int base = blockIdx.x * 1024 + t*4;
    int v[4]; int s = 0;
    #pragma unroll
    for (int q=0;q<4;q++){ int i = base+q; v[q] = (i < NN) ? (cnt[i] + 1) : 0; s += v[q]; }
    sh[t] = s; __syncthreads();
    for (int off=1; off<256; off<<=1){
        int x = (t>=off) ? sh[t-off] : 0;
        __syncthreads();
        sh[t] += x;
        __syncthreads();
    }
    int run = sh[t] - s;
    #pragma unroll
    for (int q=0;q<4;q++){ int i = base+q; if (i<NN) rowptr[i] = run; run += v[q]; }
    if (t==255) bsum[blockIdx.x] = sh[255];
}

__global__ void scan_b_kernel(int* bsum, int* rowptr, int nb) {
    if (threadIdx.x==0 && blockIdx.x==0){
        int run=0;
        for (int b=0;b<nb;b++){ int x=bsum[b]; bsum[b]=run; run+=x; }
        rowptr[NN] = run;
    }
}

__global__ void scan_c_kernel(int* __restrict__ rowptr, const int* __restrict__ bsum,
                              int* __restrict__ cnt) {
    int i = blockIdx.x*blockDim.x + threadIdx.x;
    if (i < NN){ rowptr[i] += bsum[i >> 10]; cnt[i] = 0; }
}

__global__ void scatter_kernel(const int* __restrict__ ei,
                               const int* __restrict__ rowptr, int* __restrict__ cnt,
                               int* __restrict__ col, int* __restrict__ ekey) {
    int i = blockIdx.x*blockDim.x + threadIdx.x;
    if (i >= NE + NN) return;
    int s, d;
    if (i < NE){ s = ei[i]; d = ei[NE+i]; } else { s = i - NE; d = s; }
    int pos = rowptr[d] + atomicAdd(&cnt[d], 1);
    col[pos] = s;
    ekey[pos] = i;          // original msg index: edges 0..NE-1, self-loops NE..NE+NN-1 (last)
}

// sort each row by ORIGINAL edge index -> per-dst summation order == reference add.at order
__global__ void sortrows_kernel(const int* __restrict__ rowptr,
                                int* __restrict__ col, int* __restrict__ ekey) {
    int row = blockIdx.x*blockDim.x + threadIdx.x;
    if (row >= NN) return;
    int s = rowptr[row], e = rowptr[row+1];
    for (int i=s+1; i<e; ++i){
        int kk = ekey[i], kc = col[i];
        int j = i-1;
        while (j >= s && ekey[j] > kk){ ekey[j+1]=ekey[j]; col[j+1]=col[j]; --j; }
        ekey[j+1]=kk; col[j+1]=kc;
    }
}

// nrm[pos] = dinv[src] * dinv[dst]  (single rounded fp32 mul, as reference)
__global__ void normfill_kernel(const int* __restrict__ rowptr, const int* __restrict__ col,
                                const float* __restrict__ dinv, float* __restrict__ nrm) {
    int row = blockIdx.x*blockDim.x + threadIdx.x;
    if (row >= NN) return;
    float dr = dinv[row];
    int s = rowptr[row], e = rowptr[row+1];
    for (int i=s; i<e; ++i) nrm[i] = __fmul_rn(dinv[col[i]], dr);
}

// ---------------- GEMM: Y = X @ W (+bias,relu) -- sequential-k fp32 FMA per element ----------------
template<int BIASRELU>
__global__ __launch_bounds__(256) void gemm_xw_kernel(
    const float* __restrict__ X, const float* __restrict__ W,
    const float* __restrict__ bias, float* __restrict__ Y)
{
    __shared__ float Xs[32][132];
    int t = threadIdx.x;
    int row0 = blockIdx.x * 32;
    #pragma unroll
    for (int q=0;q<4;q++){
        int f = q*1024 + t*4;
        int r = f >> 7, c = f & 127;
        *(float4*)&Xs[r][c] = *(const float4*)&X[(size_t)(row0+r)*HH + c];
    }
    __syncthreads();
    int rb = (t >> 5)*4, cb = (t & 31)*4;
    float acc[4][4];
    #pragma unroll
    for (int i=0;i<4;i++)
        #pragma unroll
        for (int j=0;j<4;j++) acc[i][j] = 0.f;
    for (int k=0;k<HH;k++){
        float a0=Xs[rb][k], a1=Xs[rb+1][k], a2=Xs[rb+2][k], a3=Xs[rb+3][k];
        float4 wv = *(const float4*)&W[(size_t)k*HH + cb];
        acc[0][0]=fmaf(a0,wv.x,acc[0][0]); acc[0][1]=fmaf(a0,wv.y,acc[0][1]);
        acc[0][2]=fmaf(a0,wv.z,acc[0][2]); acc[0][3]=fmaf(a0,wv.w,acc[0][3]);
        acc[1][0]=fmaf(a1,wv.x,acc[1][0]); acc[1][1]=fmaf(a1,wv.y,acc[1][1]);
        acc[1][2]=fmaf(a1,wv.z,acc[1][2]); acc[1][3]=fmaf(a1,wv.w,acc[1][3]);
        acc[2][0]=fmaf(a2,wv.x,acc[2][0]); acc[2][1]=fmaf(a2,wv.y,acc[2][1]);
        acc[2][2]=fmaf(a2,wv.z,acc[2][2]); acc[2][3]=fmaf(a2,wv.w,acc[2][3]);
        acc[3][0]=fmaf(a3,wv.x,acc[3][0]); acc[3][1]=fmaf(a3,wv.y,acc[3][1]);
        acc[3][2]=fmaf(a3,wv.z,acc[3][2]); acc[3][3]=fmaf(a3,wv.w,acc[3][3]);
    }
    #pragma unroll
    for (int i=0;i<4;i++){
        size_t base = (size_t)(row0+rb+i)*HH + cb;
        #pragma unroll
        for (int j=0;j<4;j++){
            float v = acc[i][j];
            if (BIASRELU) v = fmaxf(__fadd_rn(v, bias[cb+j]), 0.f);
            Y[base+j] = v;
        }
    }
}

// ---------------- aggregation + epilogue, reference-order strict fp32 ----------------
// MODE 0 (forward): Zout = Zin + relu(agg + b)
// MODE 1 (inverse): Zout = Zin - relu(agg + b); diff vs Xcur; flag-gated freeze
template<int MODE>
__global__ __launch_bounds__(256) void agg_ep_kernel(
    const float* __restrict__ XW,
    const int* __restrict__ rowptr, const int* __restrict__ col, const float* __restrict__ nrm,
    const float* __restrict__ bias,
    const float* __restrict__ Zin,
    const float* __restrict__ Xcur,
    float* __restrict__ Zout,
    double* __restrict__ partial, const int* __restrict__ flag)
{
    int node = blockIdx.x*8 + (threadIdx.x >> 5);
    int lane = threadIdx.x & 31;
    int c = lane*4;
    size_t nbase = (size_t)node*HH + c;

    if (MODE==1 && flag[0]){
        *(float4*)&Zout[nbase] = *(const float4*)&Xcur[nbase];
        if (threadIdx.x==0) partial[blockIdx.x] = 0.0;
        return;
    }

    int e = rowptr[node], end = rowptr[node+1];
    float a0=0.f,a1=0.f,a2=0.f,a3=0.f;
    for (; e < end; ++e){
        int s = col[e]; float n = nrm[e];
        float4 v = *(const float4*)&XW[(size_t)s*HH + c];
        a0 = __fadd_rn(a0, __fmul_rn(n, v.x));
        a1 = __fadd_rn(a1, __fmul_rn(n, v.y));
        a2 = __fadd_rn(a2, __fmul_rn(n, v.z));
        a3 = __fadd_rn(a3, __fmul_rn(n, v.w));
    }
    float4 bb = *(const float4*)&bias[c];
    float g0 = fmaxf(__fadd_rn(a0, bb.x), 0.f);
    float g1 = fmaxf(__fadd_rn(a1, bb.y), 0.f);
    float g2 = fmaxf(__fadd_rn(a2, bb.z), 0.f);
    float g3 = fmaxf(__fadd_rn(a3, bb.w), 0.f);
    float4 zi = *(const float4*)&Zin[nbase];
    float4 res;
    float ldiff = 0.f;
    if (MODE==0){
        res.x = __fadd_rn(zi.x, g0); res.y = __fadd_rn(zi.y, g1);
        res.z = __fadd_rn(zi.z, g2); res.w = __fadd_rn(zi.w, g3);
    } else {
        float4 xc = *(const float4*)&Xcur[nbase];
        res.x = __fsub_rn(zi.x, g0); res.y = __fsub_rn(zi.y, g1);
        res.z = __fsub_rn(zi.z, g2); res.w = __fsub_rn(zi.w, g3);
        ldiff = fabsf(res.x - xc.x) + fabsf(res.y - xc.y)
              + fabsf(res.z - xc.z) + fabsf(res.w - xc.w);
    }
    *(float4*)&Zout[nbase] = res;

    if (MODE==1){
        __shared__ float reds[256];
        int t = threadIdx.x;
        reds[t] = ldiff; __syncthreads();
        for (int off=128; off; off>>=1){
            if (t < off) reds[t] += reds[t+off];
            __syncthreads();
        }
        if (t==0) partial[blockIdx.x] = (double)reds[0];
    }
}

__global__ __launch_bounds__(256) void reduce_diff_kernel(const double* __restrict__ partial,
                                                          int* __restrict__ flag)
{
    if (flag[0]) return;
    __shared__ double sh[256];
    int t = threadIdx.x;
    double s = 0.0;
    for (int i=t; i<5000; i+=256) s += partial[i];
    sh[t] = s; __syncthreads();
    for (int off=128; off; off>>=1){
        if (t < off) sh[t] += sh[t+off];
        __syncthreads();
    }
    // mean over N*H < 1e-4  <=>  sum < 512
    if (t==0 && sh[0] < 512.0) flag[0] = 1;
}

// ---------------- head: LN(256) two-pass fp32 + MLP fp32 VALU ----------------
__global__ __launch_bounds__(256) void final_kernel(
    const float* __restrict__ zf, const float* __restrict__ zb,
    const float* __restrict__ lng, const float* __restrict__ lnb,
    const float* __restrict__ Wo1, const float* __restrict__ bo1,
    const float* __restrict__ Wo2, const float* __restrict__ bo2,
    float* __restrict__ out)
{
    __shared__ float zs[32][257];
    __shared__ float h1s[32][129];
    __shared__ float w2s[128*OUTD];
    int t = threadIdx.x;
    int node0 = blockIdx.x * 32;

    // phase 0: load z = [zf | zb]
    #pragma unroll
    for (int q=0;q<4;q++){
        int f = q*256 + t;            // 0..1023 : node = f>>5, chunk of 4 floats = f&31
        int n = f >> 5, cc = (f & 31)*4;
        *(float4*)&zs[n][cc]       = *(const float4*)&zf[(size_t)(node0+n)*HH + cc];
        *(float4*)&zs[n][128+cc]   = *(const float4*)&zb[(size_t)(node0+n)*HH + cc];
    }
    for (int i=t; i<HH*OUTD; i+=256) w2s[i] = Wo2[i];
    __syncthreads();

    // phase 1: LayerNorm, two-pass (mu, then var), 8 threads per node
    {
        int n = t >> 3, sub = t & 7;
        float s = 0.f;
        for (int k=sub*32; k<sub*32+32; ++k) s += zs[n][k];
        s += __shfl_xor(s,1); s += __shfl_xor(s,2); s += __shfl_xor(s,4);
        float mu = s * (1.f/256.f);
        float sq = 0.f;
        for (int k=sub*32; k<sub*32+32; ++k){ float d = __fsub_rn(zs[n][k], mu); sq = __fadd_rn(sq, __fmul_rn(d,d)); }
        sq += __shfl_xor(sq,1); sq += __shfl_xor(sq,2); sq += __shfl_xor(sq,4);
        float var = sq * (1.f/256.f);
        float rs = __fdiv_rn(1.0f, __fsqrt_rn(__fadd_rn(var, 1e-5f)));
        for (int k=sub*32; k<sub*32+32; ++k){
            float v = __fsub_rn(zs[n][k], mu);
            v = __fmul_rn(v, rs);
            v = __fmul_rn(v, lng[k]);
            v = __fadd_rn(v, lnb[k]);
            zs[n][k] = v;
        }
    }
    __syncthreads();

    // phase 2: h1 = relu(z @ Wo1 + bo1)   (32x128 items, sequential-k fmaf)
    for (int item = t; item < 32*HH; item += 256){
        int n = item >> 7, j = item & 127;
        float acc = 0.f;
        for (int k=0;k<256;k++) acc = fmaf(zs[n][k], Wo1[(size_t)k*HH + j], acc);
        h1s[n][j] = fmaxf(__fadd_rn(acc, bo1[j]), 0.f);
    }
    __syncthreads();

    // phase 3: out = h1 @ Wo2 + bo2
    for (int item = t; item < 32*OUTD; item += 256){
        int n = item / OUTD, o = item - n*OUTD;
        float acc = 0.f;
        for (int k=0;k<HH;k++) acc = fmaf(h1s[n][k], w2s[k*OUTD + o], acc);
        out[(size_t)(node0+n)*OUTD + o] = __fadd_rn(acc, bo2[o]);
    }
}

// ---------------- host ----------------
extern "C" void kernel_launch(void* const* d_in, const int* in_sizes, int n_in,
                              void* d_out, int out_size, void* d_ws, size_t ws_size,
                              hipStream_t stream)
{
    const float* x    = (const float*)d_in[0];
    const int*   ei   = (const int*)d_in[1];
    const float* W_in = (const float*)d_in[2];
    const float* b_in = (const float*)d_in[3];
    const float* W0   = (const float*)d_in[4];
    const float* b0   = (const float*)d_in[5];
    const float* W1   = (const float*)d_in[6];
    const float* b1   = (const float*)d_in[7];
    const float* lng  = (const float*)d_in[8];
    const float* lnb  = (const float*)d_in[9];
    const float* Wo1  = (const float*)d_in[10];
    const float* bo1  = (const float*)d_in[11];
    const float* Wo2  = (const float*)d_in[12];
    const float* bo2  = (const float*)d_in[13];
    float* out = (float*)d_out;

    char* p = (char*)d_ws;
    auto alloc = [&](size_t bytes)->char* {
        char* r = p; p += (bytes + 255) & ~(size_t)255; return r;
    };
    float* dinv   = (float*)alloc((size_t)NN*4);
    int*   cnt    = (int*)  alloc((size_t)NN*4);
    int*   rowptr = (int*)  alloc((size_t)(NN+1)*4);
    int*   bsum   = (int*)  alloc(64*4);
    int*   col    = (int*)  alloc((size_t)(NE+NN)*4);
    int*   ekey   = (int*)  alloc((size_t)(NE+NN)*4);
    float* nrm    = (float*)alloc((size_t)(NE+NN)*4);
    int*   flags  = (int*)  alloc(16);
    double* partial = (double*)alloc(5000*8);
    float* xw  = (float*)alloc((size_t)NN*HH*4);
    float* h   = (float*)alloc((size_t)NN*HH*4);
    float* zf  = (float*)alloc((size_t)NN*HH*4);
    float* F0  = (float*)alloc((size_t)NN*HH*4);
    float* F1  = (float*)alloc((size_t)NN*HH*4);

    init_ws_kernel<<<(NN+255)/256, 256, 0, stream>>>(cnt, flags);
    count_kernel<<<(NE+255)/256, 256, 0, stream>>>(ei, cnt);
    dinv_kernel<<<(NN+255)/256, 256, 0, stream>>>(cnt, dinv);
    int nb = (NN+1023)/1024;
    scan_a_kernel<<<nb, 256, 0, stream>>>(cnt, rowptr, bsum);
    scan_b_kernel<<<1, 64, 0, stream>>>(bsum, rowptr, nb);
    scan_c_kernel<<<(NN+255)/256, 256, 0, stream>>>(rowptr, bsum, cnt);
    scatter_kernel<<<(NE+NN+255)/256, 256, 0, stream>>>(ei, rowptr, cnt, col, ekey);
    sortrows_kernel<<<(NN+255)/256, 256, 0, stream>>>(rowptr, col, ekey);
    normfill_kernel<<<(NN+255)/256, 256, 0, stream>>>(rowptr, col, dinv, nrm);

    const int GT = NN/32;   // 1250 GEMM tiles
    const int GA = NN/8;    // 5000 aggregation blocks

    // h = relu(x @ W_in + b_in)
    gemm_xw_kernel<1><<<GT, 256, 0, stream>>>(x, W_in, b_in, h);

    // forward residual blocks: z_f (fp32, reference-faithful)
    for (int d=0; d<4; ++d){
        const float* Wd = (d & 1) ? W1 : W0;
        const float* bd = (d & 1) ? b1 : b0;
        const float* src = (d == 0) ? h : zf;
        gemm_xw_kernel<0><<<GT, 256, 0, stream>>>(src, Wd, nullptr, xw);
        agg_ep_kernel<0><<<GA, 256, 0, stream>>>(xw, rowptr, col, nrm, bd,
                                                 src, nullptr, zf, nullptr, nullptr);
    }

    // inverse fixed-point blocks: fp32, reference-faithful, early-exit per block
    float* I = h;
    float* P0 = F0;
    float* P1 = F1;
    for (int blk=0; blk<4; ++blk){
        const float* Wi = (blk & 1) ? W0 : W1;
        const float* bi = (blk & 1) ? b0 : b1;
        int* flagp = flags + blk;
        const float* cur = I;
        float* nxt = P0;
        for (int tt=0; tt<8; ++tt){
            gemm_xw_kernel<0><<<GT, 256, 0, stream>>>(cur, Wi, nullptr, xw);
            agg_ep_kernel<1><<<GA, 256, 0, stream>>>(xw, rowptr, col, nrm, bi,
                                                     I, cur, nxt, partial, flagp);
            reduce_diff_kernel<<<1, 256, 0, stream>>>(partial, flagp);
            cur = nxt;
            nxt = (nxt == P0) ? P1 : P0;
        }
        float* newI = (float*)cur;
        float* other = (newI == P0) ? P1 : P0;
        P1 = other;
        P0 = I;
        I = newI;
    }

    final_kernel<<<GT, 256, 0, stream>>>(zf, I, lng, lnb, Wo1, bo1, Wo2, bo2, out);
}